// Round 1
// baseline (7193.333 us; speedup 1.0000x reference)
//
#include <hip/hip_runtime.h>
#include <hip/hip_bf16.h>

#define N_NODES 100000
#define N_EDGES 1600000
#define EN (N_EDGES + N_NODES)
#define G_GRAPHS 64
#define D_IN 128
#define POS_DIM 16
#define HID 32
#define HEADS 4
#define OUT_DIM 10
#define D0 144
#define D1 128
#define LRELU_SLOPE 0.2f
#define BN_EPS 1e-5f
#define DIV_W 0.1f

// ---------------- histogram of batch -> counts[64] ----------------
__global__ void k_hist(const int* __restrict__ batch, int* __restrict__ counts, int n) {
    __shared__ int hist[G_GRAPHS];
    if (threadIdx.x < G_GRAPHS) hist[threadIdx.x] = 0;
    __syncthreads();
    for (int i = blockIdx.x * blockDim.x + threadIdx.x; i < n; i += gridDim.x * blockDim.x)
        atomicAdd(&hist[batch[i]], 1);
    __syncthreads();
    if (threadIdx.x < G_GRAPHS) atomicAdd(&counts[threadIdx.x], hist[threadIdx.x]);
}

// ---------------- scan: starts, grid = ceil(sqrt(count)) ----------------
__global__ void k_scan(const int* __restrict__ counts, int* __restrict__ starts,
                       int* __restrict__ gridg) {
    if (threadIdx.x == 0) {
        int run = 0;
        for (int g = 0; g < G_GRAPHS; ++g) {
            starts[g] = run;
            int c = counts[g];
            run += c;
            int s = (int)sqrtf((float)c);
            while ((long long)s * s < c) ++s;
            while (s > 0 && (long long)(s - 1) * (s - 1) >= c) --s;
            gridg[g] = s;
        }
    }
}

// ---------------- build h_in = [x, pos@pos_w + pos_b]  (N x 144) ----------------
__global__ void k_hin(const float* __restrict__ x, const int* __restrict__ batch,
                      const int* __restrict__ starts, const int* __restrict__ gridg,
                      const float* __restrict__ pos_w, const float* __restrict__ pos_b,
                      float* __restrict__ hin) {
    long long t = (long long)blockIdx.x * blockDim.x + threadIdx.x;
    if (t >= (long long)N_NODES * D0) return;
    int n = (int)(t / D0);
    int c = (int)(t % D0);
    if (c < D_IN) {
        hin[t] = x[(size_t)n * D_IN + c];
    } else {
        int j = c - D_IN;
        int b = batch[n];
        int local = n - starts[b];
        int g = max(gridg[b], 1);
        float denom = (float)max(g - 1, 1);
        float row = (float)(local / g);
        float col = (float)(local % g);
        float p0 = row / denom, p1 = col / denom;
        hin[t] = p0 * pos_w[j] + p1 * pos_w[POS_DIM + j] + pos_b[j];
    }
}

// ---------------- generic small GEMM: out[n][c] = sum_k in[n][k]*w[k][c] (+bias)(+=) ----------------
// block: 256 threads = 128 channels x 2 node-halves; 16 nodes per block, K <= 144
__global__ void k_gemm(const float* __restrict__ in, const float* __restrict__ w,
                       const float* __restrict__ bias, float* __restrict__ out,
                       int n, int K, int accumulate) {
    __shared__ float tile[16 * 144];
    const int tid = threadIdx.x;
    const int c = tid & 127;
    const int half = tid >> 7;
    const int base_row = blockIdx.x * 16;
    const int elems = 16 * K;
    const long long gbase = (long long)base_row * K;
    const long long limit = (long long)n * K;
    for (int idx = tid; idx < elems; idx += 256) {
        long long gi = gbase + idx;
        tile[idx] = (gi < limit) ? in[gi] : 0.f;
    }
    __syncthreads();
    float acc[8] = {0.f, 0.f, 0.f, 0.f, 0.f, 0.f, 0.f, 0.f};
    const float* tbase = &tile[half * 8 * K];
#pragma unroll 4
    for (int k = 0; k < K; ++k) {
        float wv = w[(size_t)k * 128 + c];
#pragma unroll
        for (int i = 0; i < 8; ++i)
            acc[i] = fmaf(tbase[i * K + k], wv, acc[i]);
    }
    float bv = bias ? bias[c] : 0.f;
#pragma unroll
    for (int i = 0; i < 8; ++i) {
        int row = base_row + half * 8 + i;
        if (row < n) {
            size_t o = (size_t)row * 128 + c;
            float v = acc[i] + bv;
            if (accumulate) v += out[o];
            out[o] = v;
        }
    }
}

// ---------------- per-node per-head attention logits source/dest ----------------
__global__ void k_esed(const float* __restrict__ h, const float* __restrict__ asrc,
                       const float* __restrict__ adst, float* __restrict__ es,
                       float* __restrict__ ed) {
    int t = blockIdx.x * blockDim.x + threadIdx.x;
    if (t >= N_NODES * HEADS) return;
    int n = t >> 2, hd = t & 3;
    const float* row = h + (size_t)n * D1 + hd * HID;
    const float* as = asrc + hd * HID;
    const float* ad = adst + hd * HID;
    float s = 0.f, d = 0.f;
#pragma unroll 8
    for (int j = 0; j < HID; ++j) {
        float v = row[j];
        s = fmaf(v, as[j], s);
        d = fmaf(v, ad[j], d);
    }
    es[t] = s;
    ed[t] = d;
}

// ---------------- pass A: softmax denominators via atomics (no max: f32-safe) ----------------
__global__ void k_attA(const int* __restrict__ ei, const float* __restrict__ es,
                       const float* __restrict__ ed, float* __restrict__ denom) {
    int e = blockIdx.x * blockDim.x + threadIdx.x;
    if (e >= EN) return;
    int s, d;
    if (e < N_EDGES) { s = ei[e]; d = ei[N_EDGES + e]; }
    else { s = e - N_EDGES; d = s; }
    float4 esv = reinterpret_cast<const float4*>(es)[s];
    float4 edv = reinterpret_cast<const float4*>(ed)[d];
    float ex, v;
#pragma unroll
    for (int hd = 0; hd < 4; ++hd) {
        float a = (hd == 0) ? esv.x + edv.x : (hd == 1) ? esv.y + edv.y
                : (hd == 2) ? esv.z + edv.z : esv.w + edv.w;
        v = (a > 0.f) ? a : LRELU_SLOPE * a;
        ex = expf(v);
        unsafeAtomicAdd(&denom[d * 4 + hd], ex);
    }
}

// ---------------- init aggregation buffer with bias ----------------
__global__ void k_initbias(const float* __restrict__ b, float* __restrict__ out) {
    long long t = (long long)blockIdx.x * blockDim.x + threadIdx.x;
    if (t >= (long long)N_NODES * D1) return;
    out[t] = b[t & 127];
}

// ---------------- pass B: aggregate alpha * h[src] into out[dst] ----------------
__global__ void k_attB(const int* __restrict__ ei, const float* __restrict__ es,
                       const float* __restrict__ ed, const float* __restrict__ denom,
                       const float* __restrict__ h, float* __restrict__ out) {
    long long gt = (long long)blockIdx.x * blockDim.x + threadIdx.x;
    long long e = gt >> 5;
    if (e >= EN) return;
    int lane = (int)(gt & 31);
    int s, d;
    if (e < N_EDGES) { s = ei[e]; d = ei[N_EDGES + e]; }
    else { s = (int)(e - N_EDGES); d = s; }
    int hd = lane >> 3;
    float a = es[s * 4 + hd] + ed[d * 4 + hd];
    float v = (a > 0.f) ? a : LRELU_SLOPE * a;
    float alpha = expf(v) / denom[d * 4 + hd];
    float4 hv = *reinterpret_cast<const float4*>(h + (size_t)s * D1 + lane * 4);
    float* op = out + (size_t)d * D1 + lane * 4;
    unsafeAtomicAdd(op + 0, alpha * hv.x);
    unsafeAtomicAdd(op + 1, alpha * hv.y);
    unsafeAtomicAdd(op + 2, alpha * hv.z);
    unsafeAtomicAdd(op + 3, alpha * hv.w);
}

// ---------------- diversity loss partial sums (6 head pairs) ----------------
__global__ void k_div(const float* __restrict__ h, const float* __restrict__ proj,
                      float* __restrict__ Msum) {
    int t = blockIdx.x * blockDim.x + threadIdx.x;
    float nn0 = 0, nn1 = 0, nn2 = 0, nn3 = 0;
    float d01 = 0, d02 = 0, d03 = 0, d12 = 0, d13 = 0, d23 = 0;
    if (t < N_NODES) {
        const float* row = h + (size_t)t * D1;
#pragma unroll 4
        for (int c = 0; c < HID; ++c) {
            float p0 = row[c] * proj[c];
            float p1 = row[32 + c] * proj[32 + c];
            float p2 = row[64 + c] * proj[64 + c];
            float p3 = row[96 + c] * proj[96 + c];
            nn0 = fmaf(p0, p0, nn0); nn1 = fmaf(p1, p1, nn1);
            nn2 = fmaf(p2, p2, nn2); nn3 = fmaf(p3, p3, nn3);
            d01 = fmaf(p0, p1, d01); d02 = fmaf(p0, p2, d02);
            d03 = fmaf(p0, p3, d03); d12 = fmaf(p1, p2, d12);
            d13 = fmaf(p1, p3, d13); d23 = fmaf(p2, p3, d23);
        }
    }
    float s0 = fmaxf(sqrtf(nn0), 1e-8f), s1 = fmaxf(sqrtf(nn1), 1e-8f);
    float s2 = fmaxf(sqrtf(nn2), 1e-8f), s3 = fmaxf(sqrtf(nn3), 1e-8f);
    float v[6] = { d01 / (s0 * s1), d02 / (s0 * s2), d03 / (s0 * s3),
                   d12 / (s1 * s2), d13 / (s1 * s3), d23 / (s2 * s3) };
#pragma unroll
    for (int p = 0; p < 6; ++p) {
        float x = v[p];
#pragma unroll
        for (int off = 32; off > 0; off >>= 1) x += __shfl_down(x, off, 64);
        if ((threadIdx.x & 63) == 0) unsafeAtomicAdd(&Msum[p], x);
    }
}

// ---------------- BN + ELU (in place) ----------------
__global__ void k_bnelu(float* __restrict__ h, const float* __restrict__ gamma,
                        const float* __restrict__ beta, const float* __restrict__ mean,
                        const float* __restrict__ var) {
    long long t = (long long)blockIdx.x * blockDim.x + threadIdx.x;
    if (t >= (long long)N_NODES * D1) return;
    int c = (int)(t & 127);
    float x = h[t];
    float y = (x - mean[c]) * gamma[c] * rsqrtf(var[c] + BN_EPS) + beta[c];
    h[t] = (y > 0.f) ? y : (expf(y) - 1.f);
}

// ---------------- per-graph mean pool (partial, batch sorted) ----------------
__global__ void k_pool(const float* __restrict__ h, const int* __restrict__ batch,
                       float* __restrict__ emb) {
    int c = threadIdx.x;  // 128
    int s = blockIdx.x * 32;
    if (s >= N_NODES) return;
    int e = min(s + 32, N_NODES);
    int cur = batch[s];
    float acc = 0.f;
    for (int i = s; i < e; ++i) {
        int g = batch[i];
        if (g != cur) {
            unsafeAtomicAdd(&emb[cur * 128 + c], acc);
            acc = 0.f;
            cur = g;
        }
        acc += h[(size_t)i * D1 + c];
    }
    unsafeAtomicAdd(&emb[cur * 128 + c], acc);
}

// ---------------- final: emb normalize, task head, div scalar ----------------
__global__ void k_final(const float* __restrict__ emb_ws, const int* __restrict__ counts,
                        const float* __restrict__ task_w, const float* __restrict__ task_b,
                        const float* __restrict__ Msum, float* __restrict__ out) {
    __shared__ float e_lds[G_GRAPHS * 128];
    __shared__ float cnt[G_GRAPHS];
    int tid = threadIdx.x;
    if (tid < G_GRAPHS) cnt[tid] = fmaxf((float)counts[tid], 1.f);
    __syncthreads();
    for (int i = tid; i < G_GRAPHS * 128; i += 256) {
        float v = emb_ws[i] / cnt[i >> 7];
        e_lds[i] = v;
        out[641 + i] = v;
    }
    __syncthreads();
    for (int p = tid; p < G_GRAPHS * OUT_DIM; p += 256) {
        int g = p / OUT_DIM, o = p % OUT_DIM;
        float acc = task_b[o];
#pragma unroll 8
        for (int k = 0; k < 128; ++k) acc = fmaf(e_lds[g * 128 + k], task_w[k * OUT_DIM + o], acc);
        out[p] = acc;
    }
    if (tid == 0) {
        float div = 0.f;
        for (int l = 0; l < 2; ++l) {
            float s = 0.f;
            for (int p = 0; p < 6; ++p) {
                float m = Msum[l * 6 + p] / (float)N_NODES;
                s = fmaf(m, m, s);
            }
            div += s / 6.f;
        }
        out[G_GRAPHS * OUT_DIM] = DIV_W * div;
    }
}

extern "C" void kernel_launch(void* const* d_in, const int* in_sizes, int n_in,
                              void* d_out, int out_size, void* d_ws, size_t ws_size,
                              hipStream_t stream) {
    const float* x      = (const float*)d_in[0];
    const int*   ei     = (const int*)d_in[1];
    const int*   batch  = (const int*)d_in[2];
    const float* pos_w  = (const float*)d_in[3];
    const float* pos_b  = (const float*)d_in[4];
    const float* w0     = (const float*)d_in[5];
    const float* asrc0  = (const float*)d_in[6];
    const float* adst0  = (const float*)d_in[7];
    const float* b0     = (const float*)d_in[8];
    const float* w1     = (const float*)d_in[9];
    const float* asrc1  = (const float*)d_in[10];
    const float* adst1  = (const float*)d_in[11];
    const float* b1     = (const float*)d_in[12];
    const float* bn_gamma = (const float*)d_in[13];
    const float* bn_beta  = (const float*)d_in[14];
    const float* bn_mean  = (const float*)d_in[15];
    const float* bn_var   = (const float*)d_in[16];
    const float* proj   = (const float*)d_in[17];
    const float* res_w  = (const float*)d_in[18];
    const float* res_b  = (const float*)d_in[19];
    const float* task_w = (const float*)d_in[20];
    const float* task_b = (const float*)d_in[21];
    float* out = (float*)d_out;

    // workspace layout (all f32 unless noted)
    float* bufA  = (float*)d_ws;                         // N*144  (h_in, later agg1/h2)
    float* bufB  = bufA + (size_t)N_NODES * D0;          // N*128  (h0, later h1)
    float* bufC  = bufB + (size_t)N_NODES * D1;          // N*128  (agg0 -> prev)
    float* es    = bufC + (size_t)N_NODES * D1;          // N*4
    float* ed    = es + (size_t)N_NODES * 4;             // N*4
    float* denom = ed + (size_t)N_NODES * 4;             // N*4
    float* emb   = denom + (size_t)N_NODES * 4;          // 64*128
    float* Msum  = emb + G_GRAPHS * 128;                 // 12
    int* counts  = (int*)(Msum + 12);                    // 64
    int* starts  = counts + G_GRAPHS;                    // 64
    int* gridg   = starts + G_GRAPHS;                    // 64

    const int B = 256;
    // positions
    hipMemsetAsync(counts, 0, G_GRAPHS * sizeof(int), stream);
    hipMemsetAsync(Msum, 0, 12 * sizeof(float), stream);
    k_hist<<<256, B, 0, stream>>>(batch, counts, N_NODES);
    k_scan<<<1, 64, 0, stream>>>(counts, starts, gridg);
    k_hin<<<(N_NODES * (long long)D0 + B - 1) / B, B, 0, stream>>>(
        x, batch, starts, gridg, pos_w, pos_b, bufA);

    // ---- layer 0 ----
    k_gemm<<<(N_NODES + 15) / 16, B, 0, stream>>>(bufA, w0, nullptr, bufB, N_NODES, D0, 0);
    k_esed<<<(N_NODES * HEADS + B - 1) / B, B, 0, stream>>>(bufB, asrc0, adst0, es, ed);
    hipMemsetAsync(denom, 0, (size_t)N_NODES * 4 * sizeof(float), stream);
    k_attA<<<(EN + B - 1) / B, B, 0, stream>>>(ei, es, ed, denom);
    k_initbias<<<((long long)N_NODES * D1 + B - 1) / B, B, 0, stream>>>(b0, bufC);
    k_attB<<<((long long)EN * 32 + B - 1) / B, B, 0, stream>>>(ei, es, ed, denom, bufB, bufC);
    k_div<<<(N_NODES + B - 1) / B, B, 0, stream>>>(bufC, proj, Msum);
    k_bnelu<<<((long long)N_NODES * D1 + B - 1) / B, B, 0, stream>>>(
        bufC, bn_gamma, bn_beta, bn_mean, bn_var);

    // ---- layer 1 ----  (bufC = h1_in = prev)
    k_gemm<<<(N_NODES + 15) / 16, B, 0, stream>>>(bufC, w1, nullptr, bufB, N_NODES, D1, 0);
    k_esed<<<(N_NODES * HEADS + B - 1) / B, B, 0, stream>>>(bufB, asrc1, adst1, es, ed);
    hipMemsetAsync(denom, 0, (size_t)N_NODES * 4 * sizeof(float), stream);
    k_attA<<<(EN + B - 1) / B, B, 0, stream>>>(ei, es, ed, denom);
    k_initbias<<<((long long)N_NODES * D1 + B - 1) / B, B, 0, stream>>>(b1, bufA);
    k_attB<<<((long long)EN * 32 + B - 1) / B, B, 0, stream>>>(ei, es, ed, denom, bufB, bufA);
    k_div<<<(N_NODES + B - 1) / B, B, 0, stream>>>(bufA, proj + HEADS * HID, Msum + 6);
    k_bnelu<<<((long long)N_NODES * D1 + B - 1) / B, B, 0, stream>>>(
        bufA, bn_gamma + D1, bn_beta + D1, bn_mean + D1, bn_var + D1);

    // residual: bufA += prev @ res_w + res_b
    k_gemm<<<(N_NODES + 15) / 16, B, 0, stream>>>(bufC, res_w, res_b, bufA, N_NODES, D1, 1);

    // pooling + heads
    hipMemsetAsync(emb, 0, G_GRAPHS * 128 * sizeof(float), stream);
    k_pool<<<(N_NODES + 31) / 32, 128, 0, stream>>>(bufA, batch, emb);
    k_final<<<1, B, 0, stream>>>(emb, counts, task_w, task_b, Msum, out);
}

// Round 2
// 1386.997 us; speedup vs baseline: 5.1863x; 5.1863x over previous
//
#include <hip/hip_runtime.h>
#include <hip/hip_bf16.h>

#define N_NODES 100000
#define N_EDGES 1600000
#define G_GRAPHS 64
#define D_IN 128
#define POS_DIM 16
#define HID 32
#define HEADS 4
#define OUT_DIM 10
#define D0 144
#define D1 128
#define LRELU_SLOPE 0.2f
#define BN_EPS 1e-5f
#define DIV_W 0.1f

#define SCAN_BLOCKS 98            // 98*1024 = 100352 >= N_NODES+1
#define DEG_PAD (SCAN_BLOCKS * 1024)

// ---------------- histogram of batch -> counts[64] ----------------
__global__ void k_hist(const int* __restrict__ batch, int* __restrict__ counts, int n) {
    __shared__ int hist[G_GRAPHS];
    if (threadIdx.x < G_GRAPHS) hist[threadIdx.x] = 0;
    __syncthreads();
    for (int i = blockIdx.x * blockDim.x + threadIdx.x; i < n; i += gridDim.x * blockDim.x)
        atomicAdd(&hist[batch[i]], 1);
    __syncthreads();
    if (threadIdx.x < G_GRAPHS) atomicAdd(&counts[threadIdx.x], hist[threadIdx.x]);
}

// ---------------- per-graph starts, grid = ceil(sqrt(count)) ----------------
__global__ void k_gridstats(const int* __restrict__ counts, int* __restrict__ starts,
                            int* __restrict__ gridg) {
    if (threadIdx.x == 0) {
        int run = 0;
        for (int g = 0; g < G_GRAPHS; ++g) {
            starts[g] = run;
            int c = counts[g];
            run += c;
            int s = (int)sqrtf((float)c);
            while ((long long)s * s < c) ++s;
            while (s > 0 && (long long)(s - 1) * (s - 1) >= c) --s;
            gridg[g] = s;
        }
    }
}

// ---------------- build h_in = [x, pos@pos_w + pos_b]  (N x 144) ----------------
__global__ void k_hin(const float* __restrict__ x, const int* __restrict__ batch,
                      const int* __restrict__ starts, const int* __restrict__ gridg,
                      const float* __restrict__ pos_w, const float* __restrict__ pos_b,
                      float* __restrict__ hin) {
    long long t = (long long)blockIdx.x * blockDim.x + threadIdx.x;
    if (t >= (long long)N_NODES * D0) return;
    int n = (int)(t / D0);
    int c = (int)(t % D0);
    if (c < D_IN) {
        hin[t] = x[(size_t)n * D_IN + c];
    } else {
        int j = c - D_IN;
        int b = batch[n];
        int local = n - starts[b];
        int g = max(gridg[b], 1);
        float denom = (float)max(g - 1, 1);
        float row = (float)(local / g);
        float col = (float)(local % g);
        float p0 = row / denom, p1 = col / denom;
        hin[t] = p0 * pos_w[j] + p1 * pos_w[POS_DIM + j] + pos_b[j];
    }
}

// ---------------- CSR build: degree histogram ----------------
__global__ void k_deg(const int* __restrict__ ei, int* __restrict__ deg) {
    int e = blockIdx.x * blockDim.x + threadIdx.x;
    if (e >= N_EDGES) return;
    atomicAdd(&deg[ei[N_EDGES + e]], 1);
}

// ---------------- scan step 1: block sums over 1024-elem blocks ----------------
__global__ void k_scan1(const int* __restrict__ deg, int* __restrict__ bsums) {
    __shared__ int sm[256];
    int b = blockIdx.x, t = threadIdx.x;
    int4 v = reinterpret_cast<const int4*>(deg + b * 1024)[t];
    sm[t] = v.x + v.y + v.z + v.w;
    __syncthreads();
    for (int off = 128; off > 0; off >>= 1) {
        if (t < off) sm[t] += sm[t + off];
        __syncthreads();
    }
    if (t == 0) bsums[b] = sm[0];
}

// ---------------- scan step 2: exclusive scan of block sums ----------------
__global__ void k_scan2(int* __restrict__ bsums, int nb) {
    if (threadIdx.x == 0) {
        int run = 0;
        for (int i = 0; i < nb; ++i) { int v = bsums[i]; bsums[i] = run; run += v; }
    }
}

// ---------------- scan step 3: per-block exclusive scan -> offsets + cursor ----------------
__global__ void k_scan3(const int* __restrict__ deg, const int* __restrict__ bsums,
                        int* __restrict__ offs, int* __restrict__ cursor) {
    __shared__ int sm[256];
    int b = blockIdx.x, t = threadIdx.x;
    int4 v = reinterpret_cast<const int4*>(deg + b * 1024)[t];
    int tsum = v.x + v.y + v.z + v.w;
    sm[t] = tsum;
    __syncthreads();
    for (int off = 1; off < 256; off <<= 1) {
        int add = (t >= off) ? sm[t - off] : 0;
        __syncthreads();
        sm[t] += add;
        __syncthreads();
    }
    int pre = bsums[b] + sm[t] - tsum;
    int i0 = b * 1024 + t * 4;
    int ov[4];
    ov[0] = pre; ov[1] = pre + v.x; ov[2] = ov[1] + v.y; ov[3] = ov[2] + v.z;
#pragma unroll
    for (int k = 0; k < 4; ++k) {
        int idx = i0 + k;
        if (idx <= N_NODES) {
            offs[idx] = ov[k];
            if (idx < N_NODES) cursor[idx] = ov[k];
        }
    }
}

// ---------------- CSR scatter: csr_src sorted by dst ----------------
__global__ void k_scatter(const int* __restrict__ ei, int* __restrict__ cursor,
                          int* __restrict__ csr_src) {
    int e = blockIdx.x * blockDim.x + threadIdx.x;
    if (e >= N_EDGES) return;
    int d = ei[N_EDGES + e];
    int pos = atomicAdd(&cursor[d], 1);
    csr_src[pos] = ei[e];
}

// ---------------- generic small GEMM: out[n][c] = sum_k in[n][k]*w[k][c] (+bias)(+=) ----------------
__global__ void k_gemm(const float* __restrict__ in, const float* __restrict__ w,
                       const float* __restrict__ bias, float* __restrict__ out,
                       int n, int K, int accumulate) {
    __shared__ float tile[16 * 144];
    const int tid = threadIdx.x;
    const int c = tid & 127;
    const int half = tid >> 7;
    const int base_row = blockIdx.x * 16;
    const int elems = 16 * K;
    const long long gbase = (long long)base_row * K;
    const long long limit = (long long)n * K;
    for (int idx = tid; idx < elems; idx += 256) {
        long long gi = gbase + idx;
        tile[idx] = (gi < limit) ? in[gi] : 0.f;
    }
    __syncthreads();
    float acc[8] = {0.f, 0.f, 0.f, 0.f, 0.f, 0.f, 0.f, 0.f};
    const float* tbase = &tile[half * 8 * K];
#pragma unroll 4
    for (int k = 0; k < K; ++k) {
        float wv = w[(size_t)k * 128 + c];
#pragma unroll
        for (int i = 0; i < 8; ++i)
            acc[i] = fmaf(tbase[i * K + k], wv, acc[i]);
    }
    float bv = bias ? bias[c] : 0.f;
#pragma unroll
    for (int i = 0; i < 8; ++i) {
        int row = base_row + half * 8 + i;
        if (row < n) {
            size_t o = (size_t)row * 128 + c;
            float v = acc[i] + bv;
            if (accumulate) v += out[o];
            out[o] = v;
        }
    }
}

// ---------------- per-node per-head attention logits source/dest ----------------
__global__ void k_esed(const float* __restrict__ h, const float* __restrict__ asrc,
                       const float* __restrict__ adst, float* __restrict__ es,
                       float* __restrict__ ed) {
    int t = blockIdx.x * blockDim.x + threadIdx.x;
    if (t >= N_NODES * HEADS) return;
    int n = t >> 2, hd = t & 3;
    const float* row = h + (size_t)n * D1 + hd * HID;
    const float* as = asrc + hd * HID;
    const float* ad = adst + hd * HID;
    float s = 0.f, d = 0.f;
#pragma unroll 8
    for (int j = 0; j < HID; ++j) {
        float v = row[j];
        s = fmaf(v, as[j], s);
        d = fmaf(v, ad[j], d);
    }
    es[t] = s;
    ed[t] = d;
}

// ---------------- fused CSR aggregation: out[d] = (sum exp*h[src])/sum exp + bias ----------------
// one wave per dst node; lane owns channels {2*lane, 2*lane+1} (same head: lane>>4)
__global__ void k_agg(const int* __restrict__ csr_src, const int* __restrict__ offs,
                      const float* __restrict__ es, const float* __restrict__ ed,
                      const float* __restrict__ h, const float* __restrict__ bias,
                      float* __restrict__ out) {
    int node = blockIdx.x * 4 + (threadIdx.x >> 6);
    if (node >= N_NODES) return;
    int lane = threadIdx.x & 63;
    int hd = lane >> 4;
    float edv = ed[node * 4 + hd];
    int rs = offs[node], re_ = offs[node + 1];
    float accx = 0.f, accy = 0.f, dsum = 0.f;
    for (int j = rs; j < re_; ++j) {
        int s = csr_src[j];
        float a = es[s * 4 + hd] + edv;
        float v = (a > 0.f) ? a : LRELU_SLOPE * a;
        float ex = expf(v);
        float2 hv = *reinterpret_cast<const float2*>(h + (size_t)s * D1 + lane * 2);
        accx = fmaf(ex, hv.x, accx);
        accy = fmaf(ex, hv.y, accy);
        dsum += ex;
    }
    {   // self loop
        float a = es[node * 4 + hd] + edv;
        float v = (a > 0.f) ? a : LRELU_SLOPE * a;
        float ex = expf(v);
        float2 hv = *reinterpret_cast<const float2*>(h + (size_t)node * D1 + lane * 2);
        accx = fmaf(ex, hv.x, accx);
        accy = fmaf(ex, hv.y, accy);
        dsum += ex;
    }
    float inv = 1.f / dsum;
    size_t o = (size_t)node * D1 + lane * 2;
    out[o] = fmaf(accx, inv, bias[lane * 2]);
    out[o + 1] = fmaf(accy, inv, bias[lane * 2 + 1]);
}

// ---------------- diversity loss partial sums (6 head pairs) ----------------
__global__ void k_div(const float* __restrict__ h, const float* __restrict__ proj,
                      float* __restrict__ Msum) {
    int t = blockIdx.x * blockDim.x + threadIdx.x;
    float nn0 = 0, nn1 = 0, nn2 = 0, nn3 = 0;
    float d01 = 0, d02 = 0, d03 = 0, d12 = 0, d13 = 0, d23 = 0;
    if (t < N_NODES) {
        const float* row = h + (size_t)t * D1;
#pragma unroll 4
        for (int c = 0; c < HID; ++c) {
            float p0 = row[c] * proj[c];
            float p1 = row[32 + c] * proj[32 + c];
            float p2 = row[64 + c] * proj[64 + c];
            float p3 = row[96 + c] * proj[96 + c];
            nn0 = fmaf(p0, p0, nn0); nn1 = fmaf(p1, p1, nn1);
            nn2 = fmaf(p2, p2, nn2); nn3 = fmaf(p3, p3, nn3);
            d01 = fmaf(p0, p1, d01); d02 = fmaf(p0, p2, d02);
            d03 = fmaf(p0, p3, d03); d12 = fmaf(p1, p2, d12);
            d13 = fmaf(p1, p3, d13); d23 = fmaf(p2, p3, d23);
        }
    }
    float s0 = fmaxf(sqrtf(nn0), 1e-8f), s1 = fmaxf(sqrtf(nn1), 1e-8f);
    float s2 = fmaxf(sqrtf(nn2), 1e-8f), s3 = fmaxf(sqrtf(nn3), 1e-8f);
    float v[6] = { d01 / (s0 * s1), d02 / (s0 * s2), d03 / (s0 * s3),
                   d12 / (s1 * s2), d13 / (s1 * s3), d23 / (s2 * s3) };
#pragma unroll
    for (int p = 0; p < 6; ++p) {
        float x = v[p];
#pragma unroll
        for (int off = 32; off > 0; off >>= 1) x += __shfl_down(x, off, 64);
        if ((threadIdx.x & 63) == 0) unsafeAtomicAdd(&Msum[p], x);
    }
}

// ---------------- BN + ELU (in place) ----------------
__global__ void k_bnelu(float* __restrict__ h, const float* __restrict__ gamma,
                        const float* __restrict__ beta, const float* __restrict__ mean,
                        const float* __restrict__ var) {
    long long t = (long long)blockIdx.x * blockDim.x + threadIdx.x;
    if (t >= (long long)N_NODES * D1) return;
    int c = (int)(t & 127);
    float x = h[t];
    float y = (x - mean[c]) * gamma[c] * rsqrtf(var[c] + BN_EPS) + beta[c];
    h[t] = (y > 0.f) ? y : (expf(y) - 1.f);
}

// ---------------- per-graph mean pool (partial, batch sorted) ----------------
__global__ void k_pool(const float* __restrict__ h, const int* __restrict__ batch,
                       float* __restrict__ emb) {
    int c = threadIdx.x;  // 128
    int s = blockIdx.x * 32;
    if (s >= N_NODES) return;
    int e = min(s + 32, N_NODES);
    int cur = batch[s];
    float acc = 0.f;
    for (int i = s; i < e; ++i) {
        int g = batch[i];
        if (g != cur) {
            unsafeAtomicAdd(&emb[cur * 128 + c], acc);
            acc = 0.f;
            cur = g;
        }
        acc += h[(size_t)i * D1 + c];
    }
    unsafeAtomicAdd(&emb[cur * 128 + c], acc);
}

// ---------------- final: emb normalize, task head, div scalar ----------------
__global__ void k_final(const float* __restrict__ emb_ws, const int* __restrict__ counts,
                        const float* __restrict__ task_w, const float* __restrict__ task_b,
                        const float* __restrict__ Msum, float* __restrict__ out) {
    __shared__ float e_lds[G_GRAPHS * 128];
    __shared__ float cnt[G_GRAPHS];
    int tid = threadIdx.x;
    if (tid < G_GRAPHS) cnt[tid] = fmaxf((float)counts[tid], 1.f);
    __syncthreads();
    for (int i = tid; i < G_GRAPHS * 128; i += 256) {
        float v = emb_ws[i] / cnt[i >> 7];
        e_lds[i] = v;
        out[641 + i] = v;
    }
    __syncthreads();
    for (int p = tid; p < G_GRAPHS * OUT_DIM; p += 256) {
        int g = p / OUT_DIM, o = p % OUT_DIM;
        float acc = task_b[o];
#pragma unroll 8
        for (int k = 0; k < 128; ++k) acc = fmaf(e_lds[g * 128 + k], task_w[k * OUT_DIM + o], acc);
        out[p] = acc;
    }
    if (tid == 0) {
        float div = 0.f;
        for (int l = 0; l < 2; ++l) {
            float s = 0.f;
            for (int p = 0; p < 6; ++p) {
                float m = Msum[l * 6 + p] / (float)N_NODES;
                s = fmaf(m, m, s);
            }
            div += s / 6.f;
        }
        out[G_GRAPHS * OUT_DIM] = DIV_W * div;
    }
}

extern "C" void kernel_launch(void* const* d_in, const int* in_sizes, int n_in,
                              void* d_out, int out_size, void* d_ws, size_t ws_size,
                              hipStream_t stream) {
    const float* x      = (const float*)d_in[0];
    const int*   ei     = (const int*)d_in[1];
    const int*   batch  = (const int*)d_in[2];
    const float* pos_w  = (const float*)d_in[3];
    const float* pos_b  = (const float*)d_in[4];
    const float* w0     = (const float*)d_in[5];
    const float* asrc0  = (const float*)d_in[6];
    const float* adst0  = (const float*)d_in[7];
    const float* b0     = (const float*)d_in[8];
    const float* w1     = (const float*)d_in[9];
    const float* asrc1  = (const float*)d_in[10];
    const float* adst1  = (const float*)d_in[11];
    const float* b1     = (const float*)d_in[12];
    const float* bn_gamma = (const float*)d_in[13];
    const float* bn_beta  = (const float*)d_in[14];
    const float* bn_mean  = (const float*)d_in[15];
    const float* bn_var   = (const float*)d_in[16];
    const float* proj   = (const float*)d_in[17];
    const float* res_w  = (const float*)d_in[18];
    const float* res_b  = (const float*)d_in[19];
    const float* task_w = (const float*)d_in[20];
    const float* task_b = (const float*)d_in[21];
    float* out = (float*)d_out;

    // workspace layout
    float* bufA  = (float*)d_ws;                         // N*144  (h_in; cols 128..143 later reused for csr_src; rows later agg1/h2)
    float* bufB  = bufA + (size_t)N_NODES * D0;          // N*128  (h0, later h1)
    float* bufC  = bufB + (size_t)N_NODES * D1;          // N*128  (agg0 -> prev)
    float* es    = bufC + (size_t)N_NODES * D1;          // N*4
    float* ed    = es + (size_t)N_NODES * 4;             // N*4
    float* emb   = ed + (size_t)N_NODES * 4;             // 64*128
    float* Msum  = emb + G_GRAPHS * 128;                 // 12
    int* counts  = (int*)(Msum + 12);                    // 64
    int* starts  = counts + G_GRAPHS;                    // 64
    int* gridg   = starts + G_GRAPHS;                    // 64
    int* deg     = gridg + G_GRAPHS;                     // DEG_PAD (100352)
    int* offs    = deg + DEG_PAD;                        // N+1
    int* cursor  = offs + (N_NODES + 1);                 // N
    int* bsums   = cursor + N_NODES;                     // SCAN_BLOCKS
    int* csr_src = (int*)(bufA + (size_t)N_NODES * D1);  // N*16 = 1.6M ints = E (valid after gemm0)

    const int B = 256;

    // graph stats + positions + input features
    hipMemsetAsync(counts, 0, G_GRAPHS * sizeof(int), stream);
    hipMemsetAsync(Msum, 0, 12 * sizeof(float), stream);
    hipMemsetAsync(deg, 0, DEG_PAD * sizeof(int), stream);
    k_hist<<<256, B, 0, stream>>>(batch, counts, N_NODES);
    k_gridstats<<<1, 64, 0, stream>>>(counts, starts, gridg);
    k_hin<<<((long long)N_NODES * D0 + B - 1) / B, B, 0, stream>>>(
        x, batch, starts, gridg, pos_w, pos_b, bufA);

    // gemm0 consumes bufA(h_in) -> bufB(h0)
    k_gemm<<<(N_NODES + 15) / 16, B, 0, stream>>>(bufA, w0, nullptr, bufB, N_NODES, D0, 0);

    // CSR build (bufA cols 128..143 now dead -> csr_src lives there)
    k_deg<<<(N_EDGES + B - 1) / B, B, 0, stream>>>(ei, deg);
    k_scan1<<<SCAN_BLOCKS, 256, 0, stream>>>(deg, bsums);
    k_scan2<<<1, 64, 0, stream>>>(bsums, SCAN_BLOCKS);
    k_scan3<<<SCAN_BLOCKS, 256, 0, stream>>>(deg, bsums, offs, cursor);
    k_scatter<<<(N_EDGES + B - 1) / B, B, 0, stream>>>(ei, cursor, csr_src);

    // ---- layer 0 ----
    k_esed<<<(N_NODES * HEADS + B - 1) / B, B, 0, stream>>>(bufB, asrc0, adst0, es, ed);
    k_agg<<<(N_NODES + 3) / 4, B, 0, stream>>>(csr_src, offs, es, ed, bufB, b0, bufC);
    k_div<<<(N_NODES + B - 1) / B, B, 0, stream>>>(bufC, proj, Msum);
    k_bnelu<<<((long long)N_NODES * D1 + B - 1) / B, B, 0, stream>>>(
        bufC, bn_gamma, bn_beta, bn_mean, bn_var);

    // ---- layer 1 ----  (bufC = h1_in = prev)
    k_gemm<<<(N_NODES + 15) / 16, B, 0, stream>>>(bufC, w1, nullptr, bufB, N_NODES, D1, 0);
    k_esed<<<(N_NODES * HEADS + B - 1) / B, B, 0, stream>>>(bufB, asrc1, adst1, es, ed);
    k_agg<<<(N_NODES + 3) / 4, B, 0, stream>>>(csr_src, offs, es, ed, bufB, b1, bufA);
    k_div<<<(N_NODES + B - 1) / B, B, 0, stream>>>(bufA, proj + HEADS * HID, Msum + 6);
    k_bnelu<<<((long long)N_NODES * D1 + B - 1) / B, B, 0, stream>>>(
        bufA, bn_gamma + D1, bn_beta + D1, bn_mean + D1, bn_var + D1);

    // residual: bufA += prev @ res_w + res_b
    k_gemm<<<(N_NODES + 15) / 16, B, 0, stream>>>(bufC, res_w, res_b, bufA, N_NODES, D1, 1);

    // pooling + heads
    hipMemsetAsync(emb, 0, G_GRAPHS * 128 * sizeof(float), stream);
    k_pool<<<(N_NODES + 31) / 32, 128, 0, stream>>>(bufA, batch, emb);
    k_final<<<1, B, 0, stream>>>(emb, counts, task_w, task_b, Msum, out);
}

// Round 3
// 1124.820 us; speedup vs baseline: 6.3951x; 1.2331x over previous
//
#include <hip/hip_runtime.h>
#include <hip/hip_bf16.h>

#define N_NODES 100000
#define N_EDGES 1600000
#define G_GRAPHS 64
#define D_IN 128
#define POS_DIM 16
#define HID 32
#define HEADS 4
#define OUT_DIM 10
#define D0 144
#define D1 128
#define LRELU_SLOPE 0.2f
#define BN_EPS 1e-5f
#define DIV_W 0.1f

#define SCAN_BLOCKS 98            // 98*1024 = 100352 >= N_NODES+1
#define DEG_PAD (SCAN_BLOCKS * 1024)

__device__ __forceinline__ unsigned short f2b(float f) {
    unsigned u = __float_as_uint(f);
    unsigned r = (u + 0x7FFFu + ((u >> 16) & 1u)) >> 16;
    return (unsigned short)r;
}
__device__ __forceinline__ float blo(unsigned v) { return __uint_as_float(v << 16); }
__device__ __forceinline__ float bhi(unsigned v) { return __uint_as_float(v & 0xFFFF0000u); }

// ---------------- histogram of batch -> counts[64] ----------------
__global__ void k_hist(const int* __restrict__ batch, int* __restrict__ counts, int n) {
    __shared__ int hist[G_GRAPHS];
    if (threadIdx.x < G_GRAPHS) hist[threadIdx.x] = 0;
    __syncthreads();
    for (int i = blockIdx.x * blockDim.x + threadIdx.x; i < n; i += gridDim.x * blockDim.x)
        atomicAdd(&hist[batch[i]], 1);
    __syncthreads();
    if (threadIdx.x < G_GRAPHS) atomicAdd(&counts[threadIdx.x], hist[threadIdx.x]);
}

// ---------------- per-graph starts, grid = ceil(sqrt(count)) ----------------
__global__ void k_gridstats(const int* __restrict__ counts, int* __restrict__ starts,
                            int* __restrict__ gridg) {
    if (threadIdx.x == 0) {
        int run = 0;
        for (int g = 0; g < G_GRAPHS; ++g) {
            starts[g] = run;
            int c = counts[g];
            run += c;
            int s = (int)sqrtf((float)c);
            while ((long long)s * s < c) ++s;
            while (s > 0 && (long long)(s - 1) * (s - 1) >= c) --s;
            gridg[g] = s;
        }
    }
}

// ---------------- per-node normalized grid positions ----------------
__global__ void k_pos(const int* __restrict__ batch, const int* __restrict__ starts,
                      const int* __restrict__ gridg, float2* __restrict__ pos2) {
    int t = blockIdx.x * blockDim.x + threadIdx.x;
    if (t >= N_NODES) return;
    int b = batch[t];
    int local = t - starts[b];
    int g = max(gridg[b], 1);
    float denom = (float)max(g - 1, 1);
    int r = local / g;
    int c = local - r * g;
    pos2[t] = make_float2((float)r / denom, (float)c / denom);
}

// ---------------- CSR build: degree histogram ----------------
__global__ void k_deg(const int* __restrict__ ei, int* __restrict__ deg) {
    int e = blockIdx.x * blockDim.x + threadIdx.x;
    if (e >= N_EDGES) return;
    atomicAdd(&deg[ei[N_EDGES + e]], 1);
}

__global__ void k_scan1(const int* __restrict__ deg, int* __restrict__ bsums) {
    __shared__ int sm[256];
    int b = blockIdx.x, t = threadIdx.x;
    int4 v = reinterpret_cast<const int4*>(deg + b * 1024)[t];
    sm[t] = v.x + v.y + v.z + v.w;
    __syncthreads();
    for (int off = 128; off > 0; off >>= 1) {
        if (t < off) sm[t] += sm[t + off];
        __syncthreads();
    }
    if (t == 0) bsums[b] = sm[0];
}

__global__ void k_scan2(int* __restrict__ bsums, int nb) {
    if (threadIdx.x == 0) {
        int run = 0;
        for (int i = 0; i < nb; ++i) { int v = bsums[i]; bsums[i] = run; run += v; }
    }
}

__global__ void k_scan3(const int* __restrict__ deg, const int* __restrict__ bsums,
                        int* __restrict__ offs, int* __restrict__ cursor) {
    __shared__ int sm[256];
    int b = blockIdx.x, t = threadIdx.x;
    int4 v = reinterpret_cast<const int4*>(deg + b * 1024)[t];
    int tsum = v.x + v.y + v.z + v.w;
    sm[t] = tsum;
    __syncthreads();
    for (int off = 1; off < 256; off <<= 1) {
        int add = (t >= off) ? sm[t - off] : 0;
        __syncthreads();
        sm[t] += add;
        __syncthreads();
    }
    int pre = bsums[b] + sm[t] - tsum;
    int i0 = b * 1024 + t * 4;
    int ov[4];
    ov[0] = pre; ov[1] = pre + v.x; ov[2] = ov[1] + v.y; ov[3] = ov[2] + v.z;
#pragma unroll
    for (int k = 0; k < 4; ++k) {
        int idx = i0 + k;
        if (idx <= N_NODES) {
            offs[idx] = ov[k];
            if (idx < N_NODES) cursor[idx] = ov[k];
        }
    }
}

__global__ void k_scatter(const int* __restrict__ ei, int* __restrict__ cursor,
                          int* __restrict__ csr_src) {
    int e = blockIdx.x * blockDim.x + threadIdx.x;
    if (e >= N_EDGES) return;
    int d = ei[N_EDGES + e];
    int pos = atomicAdd(&cursor[d], 1);
    csr_src[pos] = ei[e];
}

// ---------------- register-blocked GEMM: 64 rows x 128 cols / block ----------------
// POS=1: input = [x | pos2 @ pos_w + pos_b] built during staging (K=144)
// OUTMODE 0: store bf16 (no bias);  OUTMODE 1: f32 accumulate out += acc + bias
template <int K, int POS, int OUTMODE>
__global__ __launch_bounds__(256) void k_gemm2(
        const float* __restrict__ in, const float2* __restrict__ pos2,
        const float* __restrict__ posw, const float* __restrict__ posb,
        const float* __restrict__ w, const float* __restrict__ bias,
        unsigned short* __restrict__ outb, float* __restrict__ outf, int n) {
    __shared__ float At[64 * K];
    const int tid = threadIdx.x;
    const int base = blockIdx.x * 64;
    constexpr int KC4 = K / 4;
    // stage A tile
    for (int idx = tid; idx < 64 * KC4; idx += 256) {
        int row = idx / KC4, c4 = idx % KC4;
        int grow = base + row;
        float4 v = make_float4(0.f, 0.f, 0.f, 0.f);
        if (grow < n) {
            if (!POS || c4 < 32) {
                v = reinterpret_cast<const float4*>(in)[(size_t)grow * 32 + c4];
            } else {
                float2 p = pos2[grow];
                int q = c4 - 32;
                float4 w0v = reinterpret_cast<const float4*>(posw)[q];
                float4 w1v = reinterpret_cast<const float4*>(posw + POS_DIM)[q];
                float4 bv  = reinterpret_cast<const float4*>(posb)[q];
                v.x = fmaf(p.x, w0v.x, fmaf(p.y, w1v.x, bv.x));
                v.y = fmaf(p.x, w0v.y, fmaf(p.y, w1v.y, bv.y));
                v.z = fmaf(p.x, w0v.z, fmaf(p.y, w1v.z, bv.z));
                v.w = fmaf(p.x, w0v.w, fmaf(p.y, w1v.w, bv.w));
            }
        }
        *reinterpret_cast<float4*>(&At[row * K + c4 * 4]) = v;
    }
    __syncthreads();

    const int rg = tid >> 5;      // 0..7 -> rows rg*8..rg*8+7
    const int cg = tid & 31;      // cols cg*4..cg*4+3
    float acc[8][4];
#pragma unroll
    for (int i = 0; i < 8; ++i)
#pragma unroll
        for (int j = 0; j < 4; ++j) acc[i][j] = 0.f;
    const float* Ab = &At[rg * 8 * K];
    const float4* w4 = reinterpret_cast<const float4*>(w) + cg;

#pragma unroll 4
    for (int k0 = 0; k0 < K; k0 += 4) {
        float4 a[8];
#pragma unroll
        for (int i = 0; i < 8; ++i)
            a[i] = *reinterpret_cast<const float4*>(&Ab[i * K + k0]);
        float4 wv[4];
#pragma unroll
        for (int kk = 0; kk < 4; ++kk) wv[kk] = w4[(size_t)(k0 + kk) * 32];
#pragma unroll
        for (int kk = 0; kk < 4; ++kk) {
#pragma unroll
            for (int i = 0; i < 8; ++i) {
                float av = (kk == 0) ? a[i].x : (kk == 1) ? a[i].y : (kk == 2) ? a[i].z : a[i].w;
                acc[i][0] = fmaf(av, wv[kk].x, acc[i][0]);
                acc[i][1] = fmaf(av, wv[kk].y, acc[i][1]);
                acc[i][2] = fmaf(av, wv[kk].z, acc[i][2]);
                acc[i][3] = fmaf(av, wv[kk].w, acc[i][3]);
            }
        }
    }

#pragma unroll
    for (int i = 0; i < 8; ++i) {
        int grow = base + rg * 8 + i;
        if (grow >= n) continue;
        if (OUTMODE == 0) {
            ushort4 o;
            o.x = f2b(acc[i][0]); o.y = f2b(acc[i][1]);
            o.z = f2b(acc[i][2]); o.w = f2b(acc[i][3]);
            *reinterpret_cast<ushort4*>(&outb[(size_t)grow * 128 + cg * 4]) = o;
        } else {
            float4 bv = reinterpret_cast<const float4*>(bias)[cg];
            float4* op = reinterpret_cast<float4*>(&outf[(size_t)grow * 128 + cg * 4]);
            float4 cur = *op;
            cur.x += acc[i][0] + bv.x; cur.y += acc[i][1] + bv.y;
            cur.z += acc[i][2] + bv.z; cur.w += acc[i][3] + bv.w;
            *op = cur;
        }
    }
}

// ---------------- per-node per-head attention logits from bf16 h ----------------
__global__ void k_esed(const unsigned short* __restrict__ hb, const float* __restrict__ asrc,
                       const float* __restrict__ adst, float* __restrict__ es,
                       float* __restrict__ ed) {
    int t = blockIdx.x * blockDim.x + threadIdx.x;
    if (t >= N_NODES * HEADS) return;
    int n = t >> 2, hd = t & 3;
    const uint4* row = reinterpret_cast<const uint4*>(hb + (size_t)n * D1 + hd * HID);
    const float* as = asrc + hd * HID;
    const float* ad = adst + hd * HID;
    float s = 0.f, d = 0.f;
#pragma unroll
    for (int q = 0; q < 4; ++q) {
        uint4 v = row[q];
        float f[8];
        f[0] = blo(v.x); f[1] = bhi(v.x); f[2] = blo(v.y); f[3] = bhi(v.y);
        f[4] = blo(v.z); f[5] = bhi(v.z); f[6] = blo(v.w); f[7] = bhi(v.w);
#pragma unroll
        for (int i = 0; i < 8; ++i) {
            s = fmaf(f[i], as[q * 8 + i], s);
            d = fmaf(f[i], ad[q * 8 + i], d);
        }
    }
    es[t] = s;
    ed[t] = d;
}

// ---------------- fused CSR aggregation from bf16 h ----------------
// one wave per dst node; lane owns channels {2*lane, 2*lane+1} (head = lane>>4)
__global__ void k_aggb(const int* __restrict__ csr_src, const int* __restrict__ offs,
                       const float* __restrict__ es, const float* __restrict__ ed,
                       const unsigned* __restrict__ hb32, const float* __restrict__ bias,
                       float* __restrict__ out) {
    int node = blockIdx.x * 4 + (threadIdx.x >> 6);
    if (node >= N_NODES) return;
    int lane = threadIdx.x & 63;
    int hd = lane >> 4;
    float edv = ed[node * 4 + hd];
    int rs = offs[node], re_ = offs[node + 1];
    float accx = 0.f, accy = 0.f, dsum = 0.f;
    for (int j = rs; j < re_; ++j) {
        int s = csr_src[j];
        float a = es[s * 4 + hd] + edv;
        float v = (a > 0.f) ? a : LRELU_SLOPE * a;
        float ex = __expf(v);
        unsigned hv = hb32[(size_t)s * 64 + lane];
        accx = fmaf(ex, blo(hv), accx);
        accy = fmaf(ex, bhi(hv), accy);
        dsum += ex;
    }
    {   // self loop
        float a = es[node * 4 + hd] + edv;
        float v = (a > 0.f) ? a : LRELU_SLOPE * a;
        float ex = __expf(v);
        unsigned hv = hb32[(size_t)node * 64 + lane];
        accx = fmaf(ex, blo(hv), accx);
        accy = fmaf(ex, bhi(hv), accy);
        dsum += ex;
    }
    float inv = 1.f / dsum;
    float2 o;
    o.x = fmaf(accx, inv, bias[lane * 2]);
    o.y = fmaf(accy, inv, bias[lane * 2 + 1]);
    reinterpret_cast<float2*>(out)[(size_t)node * 64 + lane] = o;
}

// ---------------- diversity loss partial sums (6 head pairs) ----------------
__global__ void k_div(const float* __restrict__ h, const float* __restrict__ proj,
                      float* __restrict__ Msum) {
    int t = blockIdx.x * blockDim.x + threadIdx.x;
    float nn0 = 0, nn1 = 0, nn2 = 0, nn3 = 0;
    float d01 = 0, d02 = 0, d03 = 0, d12 = 0, d13 = 0, d23 = 0;
    if (t < N_NODES) {
        const float4* row = reinterpret_cast<const float4*>(h + (size_t)t * D1);
        const float4* pj = reinterpret_cast<const float4*>(proj);
#pragma unroll
        for (int c4 = 0; c4 < 8; ++c4) {
            float4 p0 = row[c4],      q0 = pj[c4];
            float4 p1 = row[8 + c4],  q1 = pj[8 + c4];
            float4 p2 = row[16 + c4], q2 = pj[16 + c4];
            float4 p3 = row[24 + c4], q3 = pj[24 + c4];
            p0.x *= q0.x; p0.y *= q0.y; p0.z *= q0.z; p0.w *= q0.w;
            p1.x *= q1.x; p1.y *= q1.y; p1.z *= q1.z; p1.w *= q1.w;
            p2.x *= q2.x; p2.y *= q2.y; p2.z *= q2.z; p2.w *= q2.w;
            p3.x *= q3.x; p3.y *= q3.y; p3.z *= q3.z; p3.w *= q3.w;
            nn0 += p0.x * p0.x + p0.y * p0.y + p0.z * p0.z + p0.w * p0.w;
            nn1 += p1.x * p1.x + p1.y * p1.y + p1.z * p1.z + p1.w * p1.w;
            nn2 += p2.x * p2.x + p2.y * p2.y + p2.z * p2.z + p2.w * p2.w;
            nn3 += p3.x * p3.x + p3.y * p3.y + p3.z * p3.z + p3.w * p3.w;
            d01 += p0.x * p1.x + p0.y * p1.y + p0.z * p1.z + p0.w * p1.w;
            d02 += p0.x * p2.x + p0.y * p2.y + p0.z * p2.z + p0.w * p2.w;
            d03 += p0.x * p3.x + p0.y * p3.y + p0.z * p3.z + p0.w * p3.w;
            d12 += p1.x * p2.x + p1.y * p2.y + p1.z * p2.z + p1.w * p2.w;
            d13 += p1.x * p3.x + p1.y * p3.y + p1.z * p3.z + p1.w * p3.w;
            d23 += p2.x * p3.x + p2.y * p3.y + p2.z * p3.z + p2.w * p3.w;
        }
    }
    float s0 = fmaxf(sqrtf(nn0), 1e-8f), s1 = fmaxf(sqrtf(nn1), 1e-8f);
    float s2 = fmaxf(sqrtf(nn2), 1e-8f), s3 = fmaxf(sqrtf(nn3), 1e-8f);
    float v[6] = { d01 / (s0 * s1), d02 / (s0 * s2), d03 / (s0 * s3),
                   d12 / (s1 * s2), d13 / (s1 * s3), d23 / (s2 * s3) };
#pragma unroll
    for (int p = 0; p < 6; ++p) {
        float x = v[p];
#pragma unroll
        for (int off = 32; off > 0; off >>= 1) x += __shfl_down(x, off, 64);
        if ((threadIdx.x & 63) == 0) unsafeAtomicAdd(&Msum[p], x);
    }
}

// ---------------- BN + ELU (in place, float4) ----------------
__global__ void k_bnelu(float* __restrict__ h, const float* __restrict__ gamma,
                        const float* __restrict__ beta, const float* __restrict__ mean,
                        const float* __restrict__ var) {
    long long t = (long long)blockIdx.x * blockDim.x + threadIdx.x;
    if (t >= (long long)N_NODES * 32) return;
    int c4 = (int)(t & 31);
    float4 g = reinterpret_cast<const float4*>(gamma)[c4];
    float4 b = reinterpret_cast<const float4*>(beta)[c4];
    float4 m = reinterpret_cast<const float4*>(mean)[c4];
    float4 v = reinterpret_cast<const float4*>(var)[c4];
    float4 x = reinterpret_cast<float4*>(h)[t];
    float4 y;
    y.x = (x.x - m.x) * g.x * rsqrtf(v.x + BN_EPS) + b.x;
    y.y = (x.y - m.y) * g.y * rsqrtf(v.y + BN_EPS) + b.y;
    y.z = (x.z - m.z) * g.z * rsqrtf(v.z + BN_EPS) + b.z;
    y.w = (x.w - m.w) * g.w * rsqrtf(v.w + BN_EPS) + b.w;
    y.x = (y.x > 0.f) ? y.x : (__expf(y.x) - 1.f);
    y.y = (y.y > 0.f) ? y.y : (__expf(y.y) - 1.f);
    y.z = (y.z > 0.f) ? y.z : (__expf(y.z) - 1.f);
    y.w = (y.w > 0.f) ? y.w : (__expf(y.w) - 1.f);
    reinterpret_cast<float4*>(h)[t] = y;
}

// ---------------- per-graph mean pool (partial, batch sorted) ----------------
__global__ void k_pool(const float* __restrict__ h, const int* __restrict__ batch,
                       float* __restrict__ emb) {
    int c = threadIdx.x;  // 128
    int s = blockIdx.x * 32;
    if (s >= N_NODES) return;
    int e = min(s + 32, N_NODES);
    int cur = batch[s];
    float acc = 0.f;
    for (int i = s; i < e; ++i) {
        int g = batch[i];
        if (g != cur) {
            unsafeAtomicAdd(&emb[cur * 128 + c], acc);
            acc = 0.f;
            cur = g;
        }
        acc += h[(size_t)i * D1 + c];
    }
    unsafeAtomicAdd(&emb[cur * 128 + c], acc);
}

// ---------------- final: emb normalize, task head, div scalar ----------------
__global__ void k_final(const float* __restrict__ emb_ws, const int* __restrict__ counts,
                        const float* __restrict__ task_w, const float* __restrict__ task_b,
                        const float* __restrict__ Msum, float* __restrict__ out) {
    __shared__ float e_lds[G_GRAPHS * 128];
    __shared__ float cnt[G_GRAPHS];
    int tid = threadIdx.x;
    if (tid < G_GRAPHS) cnt[tid] = fmaxf((float)counts[tid], 1.f);
    __syncthreads();
    for (int i = tid; i < G_GRAPHS * 128; i += 256) {
        float v = emb_ws[i] / cnt[i >> 7];
        e_lds[i] = v;
        out[641 + i] = v;
    }
    __syncthreads();
    for (int p = tid; p < G_GRAPHS * OUT_DIM; p += 256) {
        int g = p / OUT_DIM, o = p % OUT_DIM;
        float acc = task_b[o];
#pragma unroll 8
        for (int k = 0; k < 128; ++k) acc = fmaf(e_lds[g * 128 + k], task_w[k * OUT_DIM + o], acc);
        out[p] = acc;
    }
    if (tid == 0) {
        float div = 0.f;
        for (int l = 0; l < 2; ++l) {
            float s = 0.f;
            for (int p = 0; p < 6; ++p) {
                float m = Msum[l * 6 + p] / (float)N_NODES;
                s = fmaf(m, m, s);
            }
            div += s / 6.f;
        }
        out[G_GRAPHS * OUT_DIM] = DIV_W * div;
    }
}

extern "C" void kernel_launch(void* const* d_in, const int* in_sizes, int n_in,
                              void* d_out, int out_size, void* d_ws, size_t ws_size,
                              hipStream_t stream) {
    const float* x      = (const float*)d_in[0];
    const int*   ei     = (const int*)d_in[1];
    const int*   batch  = (const int*)d_in[2];
    const float* pos_w  = (const float*)d_in[3];
    const float* pos_b  = (const float*)d_in[4];
    const float* w0     = (const float*)d_in[5];
    const float* asrc0  = (const float*)d_in[6];
    const float* adst0  = (const float*)d_in[7];
    const float* b0     = (const float*)d_in[8];
    const float* w1     = (const float*)d_in[9];
    const float* asrc1  = (const float*)d_in[10];
    const float* adst1  = (const float*)d_in[11];
    const float* b1     = (const float*)d_in[12];
    const float* bn_gamma = (const float*)d_in[13];
    const float* bn_beta  = (const float*)d_in[14];
    const float* bn_mean  = (const float*)d_in[15];
    const float* bn_var   = (const float*)d_in[16];
    const float* proj   = (const float*)d_in[17];
    const float* res_w  = (const float*)d_in[18];
    const float* res_b  = (const float*)d_in[19];
    const float* task_w = (const float*)d_in[20];
    const float* task_b = (const float*)d_in[21];
    float* out = (float*)d_out;

    // workspace layout
    float* p = (float*)d_ws;
    unsigned short* hb = (unsigned short*)p; p += (size_t)N_NODES * 64;  // N*128 bf16
    float* abuf = p; p += (size_t)N_NODES * D1;                          // agg0 out -> prev
    float* bbuf = p; p += (size_t)N_NODES * D1;                          // agg1 out -> final h
    float* es   = p; p += (size_t)N_NODES * 4;
    float* ed   = p; p += (size_t)N_NODES * 4;
    float2* pos2 = (float2*)p; p += (size_t)N_NODES * 2;
    float* emb  = p; p += G_GRAPHS * 128;
    float* Msum = p; p += 16;
    int* counts = (int*)p;
    int* starts  = counts + G_GRAPHS;
    int* gridg   = starts + G_GRAPHS;
    int* deg     = gridg + G_GRAPHS;
    int* offs    = deg + DEG_PAD;
    int* cursor  = offs + (N_NODES + 1);
    int* bsums   = cursor + N_NODES;
    int* csr_src = bsums + 128;

    const int B = 256;

    hipMemsetAsync(counts, 0, G_GRAPHS * sizeof(int), stream);
    hipMemsetAsync(Msum, 0, 12 * sizeof(float), stream);
    hipMemsetAsync(deg, 0, DEG_PAD * sizeof(int), stream);
    k_hist<<<256, B, 0, stream>>>(batch, counts, N_NODES);
    k_gridstats<<<1, 64, 0, stream>>>(counts, starts, gridg);
    k_pos<<<(N_NODES + B - 1) / B, B, 0, stream>>>(batch, starts, gridg, pos2);

    // CSR build
    k_deg<<<(N_EDGES + B - 1) / B, B, 0, stream>>>(ei, deg);
    k_scan1<<<SCAN_BLOCKS, 256, 0, stream>>>(deg, bsums);
    k_scan2<<<1, 64, 0, stream>>>(bsums, SCAN_BLOCKS);
    k_scan3<<<SCAN_BLOCKS, 256, 0, stream>>>(deg, bsums, offs, cursor);
    k_scatter<<<(N_EDGES + B - 1) / B, B, 0, stream>>>(ei, cursor, csr_src);

    const int GB = (N_NODES + 63) / 64;

    // ---- layer 0 ----
    k_gemm2<D0, 1, 0><<<GB, 256, 0, stream>>>(x, pos2, pos_w, pos_b, w0, nullptr, hb, nullptr, N_NODES);
    k_esed<<<(N_NODES * HEADS + B - 1) / B, B, 0, stream>>>(hb, asrc0, adst0, es, ed);
    k_aggb<<<(N_NODES + 3) / 4, B, 0, stream>>>(csr_src, offs, es, ed, (const unsigned*)hb, b0, abuf);
    k_div<<<(N_NODES + B - 1) / B, B, 0, stream>>>(abuf, proj, Msum);
    k_bnelu<<<((long long)N_NODES * 32 + B - 1) / B, B, 0, stream>>>(
        abuf, bn_gamma, bn_beta, bn_mean, bn_var);

    // ---- layer 1 ---- (abuf = prev)
    k_gemm2<D1, 0, 0><<<GB, 256, 0, stream>>>(abuf, nullptr, nullptr, nullptr, w1, nullptr, hb, nullptr, N_NODES);
    k_esed<<<(N_NODES * HEADS + B - 1) / B, B, 0, stream>>>(hb, asrc1, adst1, es, ed);
    k_aggb<<<(N_NODES + 3) / 4, B, 0, stream>>>(csr_src, offs, es, ed, (const unsigned*)hb, b1, bbuf);
    k_div<<<(N_NODES + B - 1) / B, B, 0, stream>>>(bbuf, proj + HEADS * HID, Msum + 6);
    k_bnelu<<<((long long)N_NODES * 32 + B - 1) / B, B, 0, stream>>>(
        bbuf, bn_gamma + D1, bn_beta + D1, bn_mean + D1, bn_var + D1);

    // residual: bbuf += prev @ res_w + res_b
    k_gemm2<D1, 0, 1><<<GB, 256, 0, stream>>>(abuf, nullptr, nullptr, nullptr, res_w, res_b, nullptr, bbuf, N_NODES);

    // pooling + heads
    hipMemsetAsync(emb, 0, G_GRAPHS * 128 * sizeof(float), stream);
    k_pool<<<(N_NODES + 31) / 32, 128, 0, stream>>>(bbuf, batch, emb);
    k_final<<<1, B, 0, stream>>>(emb, counts, task_w, task_b, Msum, out);
}

// Round 4
// 711.966 us; speedup vs baseline: 10.1035x; 1.5799x over previous
//
#include <hip/hip_runtime.h>
#include <hip/hip_bf16.h>

#define N_NODES 100000
#define N_EDGES 1600000
#define G_GRAPHS 64
#define D_IN 128
#define POS_DIM 16
#define HID 32
#define HEADS 4
#define OUT_DIM 10
#define D0 144
#define D1 128
#define LRELU_SLOPE 0.2f
#define BN_EPS 1e-5f
#define DIV_W 0.1f

#define SCAN_BLOCKS 98            // 98*1024 = 100352 >= N_NODES+1
#define DEG_PAD (SCAN_BLOCKS * 1024)

__device__ __forceinline__ unsigned short f2b(float f) {
    unsigned u = __float_as_uint(f);
    unsigned r = (u + 0x7FFFu + ((u >> 16) & 1u)) >> 16;
    return (unsigned short)r;
}
__device__ __forceinline__ float blo(unsigned v) { return __uint_as_float(v << 16); }
__device__ __forceinline__ float bhi(unsigned v) { return __uint_as_float(v & 0xFFFF0000u); }

// ---------------- histogram of batch -> counts[64] ----------------
__global__ void k_hist(const int* __restrict__ batch, int* __restrict__ counts, int n) {
    __shared__ int hist[G_GRAPHS];
    if (threadIdx.x < G_GRAPHS) hist[threadIdx.x] = 0;
    __syncthreads();
    for (int i = blockIdx.x * blockDim.x + threadIdx.x; i < n; i += gridDim.x * blockDim.x)
        atomicAdd(&hist[batch[i]], 1);
    __syncthreads();
    if (threadIdx.x < G_GRAPHS) atomicAdd(&counts[threadIdx.x], hist[threadIdx.x]);
}

// ---------------- per-graph starts, grid = ceil(sqrt(count)) ----------------
__global__ void k_gridstats(const int* __restrict__ counts, int* __restrict__ starts,
                            int* __restrict__ gridg) {
    if (threadIdx.x == 0) {
        int run = 0;
        for (int g = 0; g < G_GRAPHS; ++g) {
            starts[g] = run;
            int c = counts[g];
            run += c;
            int s = (int)sqrtf((float)c);
            while ((long long)s * s < c) ++s;
            while (s > 0 && (long long)(s - 1) * (s - 1) >= c) --s;
            gridg[g] = s;
        }
    }
}

// ---------------- per-node normalized grid positions ----------------
__global__ void k_pos(const int* __restrict__ batch, const int* __restrict__ starts,
                      const int* __restrict__ gridg, float2* __restrict__ pos2) {
    int t = blockIdx.x * blockDim.x + threadIdx.x;
    if (t >= N_NODES) return;
    int b = batch[t];
    int local = t - starts[b];
    int g = max(gridg[b], 1);
    float denom = (float)max(g - 1, 1);
    int r = local / g;
    int c = local - r * g;
    pos2[t] = make_float2((float)r / denom, (float)c / denom);
}

// ---------------- CSR build ----------------
__global__ void k_deg(const int* __restrict__ ei, int* __restrict__ deg) {
    int e = blockIdx.x * blockDim.x + threadIdx.x;
    if (e >= N_EDGES) return;
    atomicAdd(&deg[ei[N_EDGES + e]], 1);
}

__global__ void k_scan1(const int* __restrict__ deg, int* __restrict__ bsums) {
    __shared__ int sm[256];
    int b = blockIdx.x, t = threadIdx.x;
    int4 v = reinterpret_cast<const int4*>(deg + b * 1024)[t];
    sm[t] = v.x + v.y + v.z + v.w;
    __syncthreads();
    for (int off = 128; off > 0; off >>= 1) {
        if (t < off) sm[t] += sm[t + off];
        __syncthreads();
    }
    if (t == 0) bsums[b] = sm[0];
}

__global__ void k_scan2(int* __restrict__ bsums, int nb) {
    if (threadIdx.x == 0) {
        int run = 0;
        for (int i = 0; i < nb; ++i) { int v = bsums[i]; bsums[i] = run; run += v; }
    }
}

__global__ void k_scan3(const int* __restrict__ deg, const int* __restrict__ bsums,
                        int* __restrict__ offs, int* __restrict__ cursor) {
    __shared__ int sm[256];
    int b = blockIdx.x, t = threadIdx.x;
    int4 v = reinterpret_cast<const int4*>(deg + b * 1024)[t];
    int tsum = v.x + v.y + v.z + v.w;
    sm[t] = tsum;
    __syncthreads();
    for (int off = 1; off < 256; off <<= 1) {
        int add = (t >= off) ? sm[t - off] : 0;
        __syncthreads();
        sm[t] += add;
        __syncthreads();
    }
    int pre = bsums[b] + sm[t] - tsum;
    int i0 = b * 1024 + t * 4;
    int ov[4];
    ov[0] = pre; ov[1] = pre + v.x; ov[2] = ov[1] + v.y; ov[3] = ov[2] + v.z;
#pragma unroll
    for (int k = 0; k < 4; ++k) {
        int idx = i0 + k;
        if (idx <= N_NODES) {
            offs[idx] = ov[k];
            if (idx < N_NODES) cursor[idx] = ov[k];
        }
    }
}

__global__ void k_scatter(const int* __restrict__ ei, int* __restrict__ cursor,
                          int* __restrict__ csr_src) {
    int e = blockIdx.x * blockDim.x + threadIdx.x;
    if (e >= N_EDGES) return;
    int d = ei[N_EDGES + e];
    int pos = atomicAdd(&cursor[d], 1);
    csr_src[pos] = ei[e];
}

// ---------------- register-blocked GEMM: 64 rows x 128 cols / block ----------------
// POS=1: input = [x | pos2 @ pos_w + pos_b] built during staging (K=144)
// OUTMODE 0: store bf16 (no bias);  OUTMODE 1: f32 accumulate out += acc + bias
// ES=1: fused attention logits es/ed (shfl-reduce over 8-lane col groups)
template <int K, int POS, int OUTMODE, int ES>
__global__ __launch_bounds__(256) void k_gemm2(
        const float* __restrict__ in, const float2* __restrict__ pos2,
        const float* __restrict__ posw, const float* __restrict__ posb,
        const float* __restrict__ w, const float* __restrict__ bias,
        const float* __restrict__ asrc, const float* __restrict__ adst,
        float* __restrict__ es, float* __restrict__ ed,
        unsigned short* __restrict__ outb, float* __restrict__ outf, int n) {
    __shared__ float At[64 * K];
    const int tid = threadIdx.x;
    const int base = blockIdx.x * 64;
    constexpr int KC4 = K / 4;
    // stage A tile
    for (int idx = tid; idx < 64 * KC4; idx += 256) {
        int row = idx / KC4, c4 = idx % KC4;
        int grow = base + row;
        float4 v = make_float4(0.f, 0.f, 0.f, 0.f);
        if (grow < n) {
            if (!POS || c4 < 32) {
                v = reinterpret_cast<const float4*>(in)[(size_t)grow * 32 + c4];
            } else {
                float2 p = pos2[grow];
                int q = c4 - 32;
                float4 w0v = reinterpret_cast<const float4*>(posw)[q];
                float4 w1v = reinterpret_cast<const float4*>(posw + POS_DIM)[q];
                float4 bv  = reinterpret_cast<const float4*>(posb)[q];
                v.x = fmaf(p.x, w0v.x, fmaf(p.y, w1v.x, bv.x));
                v.y = fmaf(p.x, w0v.y, fmaf(p.y, w1v.y, bv.y));
                v.z = fmaf(p.x, w0v.z, fmaf(p.y, w1v.z, bv.z));
                v.w = fmaf(p.x, w0v.w, fmaf(p.y, w1v.w, bv.w));
            }
        }
        *reinterpret_cast<float4*>(&At[row * K + c4 * 4]) = v;
    }
    __syncthreads();

    const int rg = tid >> 5;      // 0..7 -> rows rg*8..rg*8+7
    const int cg = tid & 31;      // cols cg*4..cg*4+3
    float acc[8][4];
#pragma unroll
    for (int i = 0; i < 8; ++i)
#pragma unroll
        for (int j = 0; j < 4; ++j) acc[i][j] = 0.f;
    const float* Ab = &At[rg * 8 * K];
    const float4* w4 = reinterpret_cast<const float4*>(w) + cg;

#pragma unroll 4
    for (int k0 = 0; k0 < K; k0 += 4) {
        float4 a[8];
#pragma unroll
        for (int i = 0; i < 8; ++i)
            a[i] = *reinterpret_cast<const float4*>(&Ab[i * K + k0]);
        float4 wv[4];
#pragma unroll
        for (int kk = 0; kk < 4; ++kk) wv[kk] = w4[(size_t)(k0 + kk) * 32];
#pragma unroll
        for (int kk = 0; kk < 4; ++kk) {
#pragma unroll
            for (int i = 0; i < 8; ++i) {
                float av = (kk == 0) ? a[i].x : (kk == 1) ? a[i].y : (kk == 2) ? a[i].z : a[i].w;
                acc[i][0] = fmaf(av, wv[kk].x, acc[i][0]);
                acc[i][1] = fmaf(av, wv[kk].y, acc[i][1]);
                acc[i][2] = fmaf(av, wv[kk].z, acc[i][2]);
                acc[i][3] = fmaf(av, wv[kk].w, acc[i][3]);
            }
        }
    }

    float4 av4, dv4;
    if (ES) {
        av4 = reinterpret_cast<const float4*>(asrc)[cg];
        dv4 = reinterpret_cast<const float4*>(adst)[cg];
    }

#pragma unroll
    for (int i = 0; i < 8; ++i) {
        int grow = base + rg * 8 + i;
        bool live = (grow < n);
        if (OUTMODE == 0) {
            if (live) {
                ushort4 o;
                o.x = f2b(acc[i][0]); o.y = f2b(acc[i][1]);
                o.z = f2b(acc[i][2]); o.w = f2b(acc[i][3]);
                *reinterpret_cast<ushort4*>(&outb[(size_t)grow * 128 + cg * 4]) = o;
            }
        } else {
            if (live) {
                float4 bv = reinterpret_cast<const float4*>(bias)[cg];
                float4* op = reinterpret_cast<float4*>(&outf[(size_t)grow * 128 + cg * 4]);
                float4 cur = *op;
                cur.x += acc[i][0] + bv.x; cur.y += acc[i][1] + bv.y;
                cur.z += acc[i][2] + bv.z; cur.w += acc[i][3] + bv.w;
                *op = cur;
            }
        }
        if (ES) {
            // attention logits: reduce 8 lanes (cg&7) spanning one head's 32 cols
            float ps = acc[i][0] * av4.x + acc[i][1] * av4.y + acc[i][2] * av4.z + acc[i][3] * av4.w;
            float pd = acc[i][0] * dv4.x + acc[i][1] * dv4.y + acc[i][2] * dv4.z + acc[i][3] * dv4.w;
            ps += __shfl_xor(ps, 1); pd += __shfl_xor(pd, 1);
            ps += __shfl_xor(ps, 2); pd += __shfl_xor(pd, 2);
            ps += __shfl_xor(ps, 4); pd += __shfl_xor(pd, 4);
            if ((cg & 7) == 0 && live) {
                es[grow * 4 + (cg >> 3)] = ps;
                ed[grow * 4 + (cg >> 3)] = pd;
            }
        }
    }
}

// ---------------- fused CSR aggregation from bf16 h (edge loop unrolled x4) ----------------
// one wave per dst node; lane owns channels {2*lane, 2*lane+1} (head = lane>>4)
__global__ void k_aggb(const int* __restrict__ csr_src, const int* __restrict__ offs,
                       const float* __restrict__ es, const float* __restrict__ ed,
                       const unsigned* __restrict__ hb32, const float* __restrict__ bias,
                       float* __restrict__ out) {
    int node = blockIdx.x * 4 + (threadIdx.x >> 6);
    if (node >= N_NODES) return;
    int lane = threadIdx.x & 63;
    int hd = lane >> 4;
    float edv = ed[node * 4 + hd];
    int rs = offs[node], re_ = offs[node + 1];
    float ax0 = 0.f, ay0 = 0.f, ds0 = 0.f;
    float ax1 = 0.f, ay1 = 0.f, ds1 = 0.f;
    int j = rs;
    for (; j + 4 <= re_; j += 4) {
        int s0 = csr_src[j + 0];
        int s1 = csr_src[j + 1];
        int s2 = csr_src[j + 2];
        int s3 = csr_src[j + 3];
        float e0 = es[s0 * 4 + hd];
        float e1 = es[s1 * 4 + hd];
        float e2 = es[s2 * 4 + hd];
        float e3 = es[s3 * 4 + hd];
        unsigned q0 = hb32[(size_t)s0 * 64 + lane];
        unsigned q1 = hb32[(size_t)s1 * 64 + lane];
        unsigned q2 = hb32[(size_t)s2 * 64 + lane];
        unsigned q3 = hb32[(size_t)s3 * 64 + lane];
        e0 += edv; e1 += edv; e2 += edv; e3 += edv;
        e0 = (e0 > 0.f) ? e0 : LRELU_SLOPE * e0;
        e1 = (e1 > 0.f) ? e1 : LRELU_SLOPE * e1;
        e2 = (e2 > 0.f) ? e2 : LRELU_SLOPE * e2;
        e3 = (e3 > 0.f) ? e3 : LRELU_SLOPE * e3;
        float x0 = __expf(e0), x1 = __expf(e1), x2 = __expf(e2), x3 = __expf(e3);
        ax0 = fmaf(x0, blo(q0), ax0); ay0 = fmaf(x0, bhi(q0), ay0);
        ax1 = fmaf(x1, blo(q1), ax1); ay1 = fmaf(x1, bhi(q1), ay1);
        ax0 = fmaf(x2, blo(q2), ax0); ay0 = fmaf(x2, bhi(q2), ay0);
        ax1 = fmaf(x3, blo(q3), ax1); ay1 = fmaf(x3, bhi(q3), ay1);
        ds0 += x0 + x2;
        ds1 += x1 + x3;
    }
    for (; j < re_; ++j) {
        int s = csr_src[j];
        float a = es[s * 4 + hd] + edv;
        float v = (a > 0.f) ? a : LRELU_SLOPE * a;
        float ex = __expf(v);
        unsigned hv = hb32[(size_t)s * 64 + lane];
        ax0 = fmaf(ex, blo(hv), ax0);
        ay0 = fmaf(ex, bhi(hv), ay0);
        ds0 += ex;
    }
    {   // self loop
        float a = es[node * 4 + hd] + edv;
        float v = (a > 0.f) ? a : LRELU_SLOPE * a;
        float ex = __expf(v);
        unsigned hv = hb32[(size_t)node * 64 + lane];
        ax0 = fmaf(ex, blo(hv), ax0);
        ay0 = fmaf(ex, bhi(hv), ay0);
        ds0 += ex;
    }
    float inv = 1.f / (ds0 + ds1);
    float2 o;
    o.x = fmaf(ax0 + ax1, inv, bias[lane * 2]);
    o.y = fmaf(ay0 + ay1, inv, bias[lane * 2 + 1]);
    reinterpret_cast<float2*>(out)[(size_t)node * 64 + lane] = o;
}

// ---------------- fused diversity loss + BN + ELU (wave per node, grid-stride) ----------------
__global__ __launch_bounds__(256) void k_divbn(
        float* __restrict__ h, const float* __restrict__ proj,
        const float* __restrict__ gamma, const float* __restrict__ beta,
        const float* __restrict__ mean, const float* __restrict__ var,
        float* __restrict__ Msum) {
    __shared__ float sm[6];
    int tid = threadIdx.x;
    if (tid < 6) sm[tid] = 0.f;
    __syncthreads();
    int lane = tid & 63;
    int wid = tid >> 6;
    float2 pj = reinterpret_cast<const float2*>(proj)[lane];
    float2 g2 = reinterpret_cast<const float2*>(gamma)[lane];
    float2 b2 = reinterpret_cast<const float2*>(beta)[lane];
    float2 m2 = reinterpret_cast<const float2*>(mean)[lane];
    float2 v2 = reinterpret_cast<const float2*>(var)[lane];
    float scx = g2.x * rsqrtf(v2.x + BN_EPS);
    float scy = g2.y * rsqrtf(v2.y + BN_EPS);
    float accA = 0.f, accB = 0.f, accC = 0.f;
    for (int node = blockIdx.x * 4 + wid; node < N_NODES; node += gridDim.x * 4) {
        float2 hv = reinterpret_cast<float2*>(h)[(size_t)node * 64 + lane];
        float px = hv.x * pj.x, py = hv.y * pj.y;
        float nn = px * px + py * py;
        nn += __shfl_xor(nn, 1); nn += __shfl_xor(nn, 2);
        nn += __shfl_xor(nn, 4); nn += __shfl_xor(nn, 8);
        float ox = __shfl_xor(px, 16), oy = __shfl_xor(py, 16);
        float d16 = px * ox + py * oy;
        ox = __shfl_xor(px, 32); oy = __shfl_xor(py, 32);
        float d32 = px * ox + py * oy;
        ox = __shfl_xor(px, 48); oy = __shfl_xor(py, 48);
        float d48 = px * ox + py * oy;
        d16 += __shfl_xor(d16, 1); d16 += __shfl_xor(d16, 2);
        d16 += __shfl_xor(d16, 4); d16 += __shfl_xor(d16, 8);
        d32 += __shfl_xor(d32, 1); d32 += __shfl_xor(d32, 2);
        d32 += __shfl_xor(d32, 4); d32 += __shfl_xor(d32, 8);
        d48 += __shfl_xor(d48, 1); d48 += __shfl_xor(d48, 2);
        d48 += __shfl_xor(d48, 4); d48 += __shfl_xor(d48, 8);
        float n_own = fmaxf(sqrtf(nn), 1e-8f);
        float n16 = fmaxf(sqrtf(__shfl_xor(nn, 16)), 1e-8f);
        float n32 = fmaxf(sqrtf(__shfl_xor(nn, 32)), 1e-8f);
        float n48 = fmaxf(sqrtf(__shfl_xor(nn, 48)), 1e-8f);
        accA += d16 / (n_own * n16);
        accB += d32 / (n_own * n32);
        accC += d48 / (n_own * n48);
        // BN + ELU
        float yx = (hv.x - m2.x) * scx + b2.x;
        float yy = (hv.y - m2.y) * scy + b2.y;
        yx = (yx > 0.f) ? yx : (__expf(yx) - 1.f);
        yy = (yy > 0.f) ? yy : (__expf(yy) - 1.f);
        reinterpret_cast<float2*>(h)[(size_t)node * 64 + lane] = make_float2(yx, yy);
    }
    int g = lane >> 4;
    if ((lane & 15) == 0) {
        if (g == 0) {
            atomicAdd(&sm[0], accA);   // pair (0,1)
            atomicAdd(&sm[1], accB);   // pair (0,2)
            atomicAdd(&sm[2], accC);   // pair (0,3)
        } else if (g == 1) {
            atomicAdd(&sm[4], accB);   // pair (1,3)
            atomicAdd(&sm[3], accC);   // pair (1,2)
        } else if (g == 2) {
            atomicAdd(&sm[5], accA);   // pair (2,3)
        }
    }
    __syncthreads();
    if (tid < 6) unsafeAtomicAdd(&Msum[tid], sm[tid]);
}

// ---------------- per-graph mean pool (partial, batch sorted) ----------------
__global__ void k_pool(const float* __restrict__ h, const int* __restrict__ batch,
                       float* __restrict__ emb) {
    int c = threadIdx.x;  // 128
    int s = blockIdx.x * 32;
    if (s >= N_NODES) return;
    int e = min(s + 32, N_NODES);
    int cur = batch[s];
    float acc = 0.f;
    for (int i = s; i < e; ++i) {
        int g = batch[i];
        if (g != cur) {
            unsafeAtomicAdd(&emb[cur * 128 + c], acc);
            acc = 0.f;
            cur = g;
        }
        acc += h[(size_t)i * D1 + c];
    }
    unsafeAtomicAdd(&emb[cur * 128 + c], acc);
}

// ---------------- final: emb normalize, task head, div scalar ----------------
__global__ void k_final(const float* __restrict__ emb_ws, const int* __restrict__ counts,
                        const float* __restrict__ task_w, const float* __restrict__ task_b,
                        const float* __restrict__ Msum, float* __restrict__ out) {
    __shared__ float e_lds[G_GRAPHS * 128];
    __shared__ float cnt[G_GRAPHS];
    int tid = threadIdx.x;
    if (tid < G_GRAPHS) cnt[tid] = fmaxf((float)counts[tid], 1.f);
    __syncthreads();
    for (int i = tid; i < G_GRAPHS * 128; i += 256) {
        float v = emb_ws[i] / cnt[i >> 7];
        e_lds[i] = v;
        out[641 + i] = v;
    }
    __syncthreads();
    for (int p = tid; p < G_GRAPHS * OUT_DIM; p += 256) {
        int g = p / OUT_DIM, o = p % OUT_DIM;
        float acc = task_b[o];
#pragma unroll 8
        for (int k = 0; k < 128; ++k) acc = fmaf(e_lds[g * 128 + k], task_w[k * OUT_DIM + o], acc);
        out[p] = acc;
    }
    if (tid == 0) {
        float div = 0.f;
        for (int l = 0; l < 2; ++l) {
            float s = 0.f;
            for (int p = 0; p < 6; ++p) {
                float m = Msum[l * 6 + p] / (float)N_NODES;
                s = fmaf(m, m, s);
            }
            div += s / 6.f;
        }
        out[G_GRAPHS * OUT_DIM] = DIV_W * div;
    }
}

extern "C" void kernel_launch(void* const* d_in, const int* in_sizes, int n_in,
                              void* d_out, int out_size, void* d_ws, size_t ws_size,
                              hipStream_t stream) {
    const float* x      = (const float*)d_in[0];
    const int*   ei     = (const int*)d_in[1];
    const int*   batch  = (const int*)d_in[2];
    const float* pos_w  = (const float*)d_in[3];
    const float* pos_b  = (const float*)d_in[4];
    const float* w0     = (const float*)d_in[5];
    const float* asrc0  = (const float*)d_in[6];
    const float* adst0  = (const float*)d_in[7];
    const float* b0     = (const float*)d_in[8];
    const float* w1     = (const float*)d_in[9];
    const float* asrc1  = (const float*)d_in[10];
    const float* adst1  = (const float*)d_in[11];
    const float* b1     = (const float*)d_in[12];
    const float* bn_gamma = (const float*)d_in[13];
    const float* bn_beta  = (const float*)d_in[14];
    const float* bn_mean  = (const float*)d_in[15];
    const float* bn_var   = (const float*)d_in[16];
    const float* proj   = (const float*)d_in[17];
    const float* res_w  = (const float*)d_in[18];
    const float* res_b  = (const float*)d_in[19];
    const float* task_w = (const float*)d_in[20];
    const float* task_b = (const float*)d_in[21];
    float* out = (float*)d_out;

    // workspace layout
    float* p = (float*)d_ws;
    unsigned short* hb = (unsigned short*)p; p += (size_t)N_NODES * 64;  // N*128 bf16
    float* abuf = p; p += (size_t)N_NODES * D1;                          // agg0 out -> prev
    float* bbuf = p; p += (size_t)N_NODES * D1;                          // agg1 out -> final h
    float* es   = p; p += (size_t)N_NODES * 4;
    float* ed   = p; p += (size_t)N_NODES * 4;
    float2* pos2 = (float2*)p; p += (size_t)N_NODES * 2;
    float* emb  = p; p += G_GRAPHS * 128;
    float* Msum = p; p += 16;
    int* counts = (int*)p;
    int* starts  = counts + G_GRAPHS;
    int* gridg   = starts + G_GRAPHS;
    int* deg     = gridg + G_GRAPHS;
    int* offs    = deg + DEG_PAD;
    int* cursor  = offs + (N_NODES + 1);
    int* bsums   = cursor + N_NODES;
    int* csr_src = bsums + 128;

    const int B = 256;

    hipMemsetAsync(counts, 0, G_GRAPHS * sizeof(int), stream);
    hipMemsetAsync(Msum, 0, 12 * sizeof(float), stream);
    hipMemsetAsync(deg, 0, DEG_PAD * sizeof(int), stream);
    k_hist<<<256, B, 0, stream>>>(batch, counts, N_NODES);
    k_gridstats<<<1, 64, 0, stream>>>(counts, starts, gridg);
    k_pos<<<(N_NODES + B - 1) / B, B, 0, stream>>>(batch, starts, gridg, pos2);

    // CSR build
    k_deg<<<(N_EDGES + B - 1) / B, B, 0, stream>>>(ei, deg);
    k_scan1<<<SCAN_BLOCKS, 256, 0, stream>>>(deg, bsums);
    k_scan2<<<1, 64, 0, stream>>>(bsums, SCAN_BLOCKS);
    k_scan3<<<SCAN_BLOCKS, 256, 0, stream>>>(deg, bsums, offs, cursor);
    k_scatter<<<(N_EDGES + B - 1) / B, B, 0, stream>>>(ei, cursor, csr_src);

    const int GB = (N_NODES + 63) / 64;

    // ---- layer 0 ----
    k_gemm2<D0, 1, 0, 1><<<GB, 256, 0, stream>>>(
        x, pos2, pos_w, pos_b, w0, nullptr, asrc0, adst0, es, ed, hb, nullptr, N_NODES);
    k_aggb<<<(N_NODES + 3) / 4, B, 0, stream>>>(csr_src, offs, es, ed, (const unsigned*)hb, b0, abuf);
    k_divbn<<<1024, B, 0, stream>>>(abuf, proj, bn_gamma, bn_beta, bn_mean, bn_var, Msum);

    // ---- layer 1 ---- (abuf = prev)
    k_gemm2<D1, 0, 0, 1><<<GB, 256, 0, stream>>>(
        abuf, nullptr, nullptr, nullptr, w1, nullptr, asrc1, adst1, es, ed, hb, nullptr, N_NODES);
    k_aggb<<<(N_NODES + 3) / 4, B, 0, stream>>>(csr_src, offs, es, ed, (const unsigned*)hb, b1, bbuf);
    k_divbn<<<1024, B, 0, stream>>>(bbuf, proj + HEADS * HID, bn_gamma + D1, bn_beta + D1,
                                    bn_mean + D1, bn_var + D1, Msum + 6);

    // residual: bbuf += prev @ res_w + res_b
    k_gemm2<D1, 0, 1, 0><<<GB, 256, 0, stream>>>(
        abuf, nullptr, nullptr, nullptr, res_w, res_b, nullptr, nullptr, nullptr, nullptr,
        nullptr, bbuf, N_NODES);

    // pooling + heads
    hipMemsetAsync(emb, 0, G_GRAPHS * 128 * sizeof(float), stream);
    k_pool<<<(N_NODES + 31) / 32, 128, 0, stream>>>(bbuf, batch, emb);
    k_final<<<1, B, 0, stream>>>(emb, counts, task_w, task_b, Msum, out);
}